// Round 3
// baseline (2722.324 us; speedup 1.0000x reference)
//
#include <hip/hip_runtime.h>

typedef float f32x4 __attribute__((ext_vector_type(4)));
typedef short s16x8 __attribute__((ext_vector_type(8)));
typedef unsigned short u16;

#define NST    2048
#define KDIM   2112
#define NYD    128
#define NUD    64
#define BD     256
#define NSTEP  80

__device__ __forceinline__ u16 f2bf(float f) {
  unsigned int u = __builtin_bit_cast(unsigned int, f);
  u = (u + 0x7FFFu + ((u >> 16) & 1u)) >> 16;
  return (u16)u;
}

__device__ __forceinline__ float tanh_fast(float x) {
  float ax = __builtin_fabsf(x);
  float e  = __expf(-2.0f * ax);
  float r  = (1.0f - e) / (1.0f + e);
  return __builtin_copysignf(r, x);
}

__device__ __forceinline__ void gl_lds16(const u16* g, u16* l) {
  __builtin_amdgcn_global_load_lds(
      (const __attribute__((address_space(1))) unsigned int*)g,
      (__attribute__((address_space(3))) unsigned int*)l, 16, 0, 0);
}

__device__ __forceinline__ f32x4 MF(s16x8 a, s16x8 b, f32x4 c) {
  return __builtin_amdgcn_mfma_f32_16x16x32_bf16(a, b, c, 0, 0, 0);
}

__device__ __forceinline__ void waitge(int* p, int v) {
  int g = 0;
  while (__hip_atomic_load(p, __ATOMIC_RELAXED, __HIP_MEMORY_SCOPE_AGENT) < v) {
    __builtin_amdgcn_s_sleep(2);
    if (++g > (1 << 24)) break;
  }
}

// flags: rdycnt ints [0,128) (8 counters stride 16, init 16); pseq [2048,4096);
//        consumed [4096,6144); xdone [6144,7424). All others 0.
__global__ void k_init(int* flags) {
  int i = blockIdx.x * 256 + threadIdx.x;
  if (i < 7424) flags[i] = (i < 128 && (i & 15) == 0) ? 16 : 0;
}

// A[2112][2048] f32 -> At[2048][2112] bf16 (At[n][k] = A[k][n])
__global__ void k_prepA(const float* __restrict__ A, u16* __restrict__ At) {
  __shared__ float tile[64][65];
  int nbase = blockIdx.x * 64;
  int kbase = blockIdx.y * 64;
  int tx = threadIdx.x & 63;
  int ty = threadIdx.x >> 6;
  for (int r = 0; r < 64; r += 4)
    tile[r + ty][tx] = A[(size_t)(kbase + r + ty) * NST + nbase + tx];
  __syncthreads();
  for (int r = 0; r < 64; r += 4) {
    int ni = r + ty;
    At[(size_t)(nbase + ni) * KDIM + kbase + tx] = f2bf(tile[tx][ni]);
  }
}

// X_0 state part = tanh(teacherforce(init, Y0)); out[0] = err0
__global__ void k_prepX0(const float* __restrict__ Y, const float* __restrict__ init,
                         u16* __restrict__ X1, float* __restrict__ out) {
  int m = blockIdx.x;
  int c = blockIdx.y * 256 + threadIdx.x;   // < 2048
  float v;
  if (c < NYD) {
    float y = Y[(size_t)m * NYD + c];
    out[(size_t)m * NYD + c] = init[c] - y;
    v = y;
  } else v = init[c];
  X1[(size_t)m * NST + c] = f2bf(tanh_fast(v));
}

// Xu[t][m][u] = tanh(U[t][m][u])
__global__ void k_prepXu(const float* __restrict__ U, u16* __restrict__ Xu) {
  int i = blockIdx.x * 256 + threadIdx.x;
  if (i < NSTEP * BD * NUD) Xu[i] = f2bf(tanh_fast(U[i]));
}

// ---- persistent kernel: 79 steps. 256 WGs = 32 j (64 cols) x 2 ks (K half) x 4 mb (64 rows).
// XCD = w&7 = j&7: owner (ks=0) and partner (ks=1) of a tile share an XCD.
__global__ void __launch_bounds__(256, 1)
k_persist(const u16* __restrict__ At, u16* __restrict__ Xp0, u16* __restrict__ Xp1,
          u16* __restrict__ Xp2, const u16* __restrict__ Xu,
          float* __restrict__ partial, int* rdycnt, int* pseq, int* consumed,
          int* xdone, const float* __restrict__ Y, float* __restrict__ out) {
  __shared__ u16 ldsX[3][4096];   // 3 x 8KB pair buffers (64 rows x 64 k bf16)

  const int w = blockIdx.x;
  const int j = w & 31, ks = (w >> 5) & 1, mb = w >> 6;
  const int tid = threadIdx.x, wv = tid >> 6, lane = tid & 63;
  const int l15 = lane & 15, lg = lane >> 4;
  const int wr = wv >> 1, wc = wv & 1;       // wave tile: 32 rows x 32 cols
  const int m0 = mb * 64, n0 = j * 64, k0 = ks * 1024;
  const int fidx = j * 4 + mb;
  const int rdy = (mb * 2 + ks) * 16;        // counter this WG polls
  const int rel = (mb * 2 + (j >> 4)) * 16;  // counter the owner bumps

  // ---- B (A^T) preload into registers: 32 chunks (+2 U chunks for ks=1)
  s16x8 b[68];
  {
    const u16* base = At + (size_t)(n0 + wc * 32 + l15) * KDIM + lg * 8;
#pragma unroll
    for (int kc = 0; kc < 32; ++kc) {
      b[kc * 2 + 0] = *(const s16x8*)(base + k0 + kc * 32);
      b[kc * 2 + 1] = *(const s16x8*)(base + (size_t)16 * KDIM + k0 + kc * 32);
    }
    if (ks) {
#pragma unroll
      for (int c = 0; c < 2; ++c) {
        b[64 + c * 2 + 0] = *(const s16x8*)(base + 2048 + c * 32);
        b[64 + c * 2 + 1] = *(const s16x8*)(base + (size_t)16 * KDIM + 2048 + c * 32);
      }
    }
  }

#define STAGE_PAIR(P, B_) do {                                                      \
    const u16* s_ = xsrc + (size_t)(m0 + (tid >> 2)) * NST + k0 + (P) * 64 +        \
                    (tid & 3) * 8;                                                  \
    gl_lds16(s_,      &ldsX[B_][(tid >> 6) * 512]);                                 \
    gl_lds16(s_ + 32, &ldsX[B_][2048 + (tid >> 6) * 512]);                          \
  } while (0)

#define PAIR_BODY(P, VM) do {                                                       \
    asm volatile("s_waitcnt vmcnt(" #VM ")" ::: "memory");                          \
    __builtin_amdgcn_sched_barrier(0);                                              \
    __builtin_amdgcn_s_barrier();                                                   \
    __builtin_amdgcn_sched_barrier(0);                                              \
    const u16* xq = &ldsX[(P) % 3][0];                                              \
    s16x8 a00 = *(const s16x8*)(xq + (wr * 32 + l15) * 32 + lg * 8);                \
    s16x8 a10 = *(const s16x8*)(xq + (wr * 32 + 16 + l15) * 32 + lg * 8);           \
    s16x8 a01 = *(const s16x8*)(xq + 2048 + (wr * 32 + l15) * 32 + lg * 8);         \
    s16x8 a11 = *(const s16x8*)(xq + 2048 + (wr * 32 + 16 + l15) * 32 + lg * 8);    \
    acc00 = MF(a00, b[(P) * 4 + 0], acc00);                                         \
    acc01 = MF(a00, b[(P) * 4 + 1], acc01);                                         \
    acc10 = MF(a10, b[(P) * 4 + 0], acc10);                                         \
    acc11 = MF(a10, b[(P) * 4 + 1], acc11);                                         \
    acc00 = MF(a01, b[(P) * 4 + 2], acc00);                                         \
    acc01 = MF(a01, b[(P) * 4 + 3], acc01);                                         \
    acc10 = MF(a11, b[(P) * 4 + 2], acc10);                                         \
    acc11 = MF(a11, b[(P) * 4 + 3], acc11);                                         \
    __builtin_amdgcn_sched_barrier(0);                                              \
    if ((P) <= 13) STAGE_PAIR((P) + 2, ((P) + 2) % 3);                              \
    __builtin_amdgcn_sched_barrier(0);                                              \
  } while (0)

  for (int tau = 1; tau < NSTEP; ++tau) {
    int r3 = tau % 3, n3 = (tau + 1) % 3;
    const u16* xsrc = r3 == 0 ? Xp0 : r3 == 1 ? Xp1 : Xp2;
    u16* xdst = n3 == 0 ? Xp0 : n3 == 1 ? Xp1 : Xp2;

    // RAW: wait until all 16 producers of this K-half finished step tau-1
    waitge(&rdycnt[rdy], 16 * tau);
    __builtin_amdgcn_fence(__ATOMIC_ACQUIRE, "agent");

    STAGE_PAIR(0, 0);
    STAGE_PAIR(1, 1);

    f32x4 acc00 = {0.f, 0.f, 0.f, 0.f}, acc01 = {0.f, 0.f, 0.f, 0.f};
    f32x4 acc10 = {0.f, 0.f, 0.f, 0.f}, acc11 = {0.f, 0.f, 0.f, 0.f};

    PAIR_BODY(0, 2);  PAIR_BODY(1, 2);  PAIR_BODY(2, 2);  PAIR_BODY(3, 2);
    PAIR_BODY(4, 2);  PAIR_BODY(5, 2);  PAIR_BODY(6, 2);  PAIR_BODY(7, 2);
    PAIR_BODY(8, 2);  PAIR_BODY(9, 2);  PAIR_BODY(10, 2); PAIR_BODY(11, 2);
    PAIR_BODY(12, 2); PAIR_BODY(13, 2); PAIR_BODY(14, 2); PAIR_BODY(15, 0);

    if (ks) {  // U tail: k 2048..2112, X part = tanh(U[tau-1]) (precomputed)
      const u16* ub = Xu + (size_t)(tau - 1) * (BD * NUD) +
                      (size_t)(m0 + wr * 32 + l15) * NUD + lg * 8;
      s16x8 u00 = *(const s16x8*)(ub);
      s16x8 u10 = *(const s16x8*)(ub + 16 * NUD);
      s16x8 u01 = *(const s16x8*)(ub + 32);
      s16x8 u11 = *(const s16x8*)(ub + 16 * NUD + 32);
      acc00 = MF(u00, b[64], acc00); acc01 = MF(u00, b[65], acc01);
      acc10 = MF(u10, b[64], acc10); acc11 = MF(u10, b[65], acc11);
      acc00 = MF(u01, b[66], acc00); acc01 = MF(u01, b[67], acc01);
      acc10 = MF(u11, b[66], acc10); acc11 = MF(u11, b[67], acc11);
    }

    __syncthreads();   // all waves done reading xsrc (drains vm/lgkm)
    if (tid == 0)
      __hip_atomic_fetch_add(&xdone[tau * 16], 1, __ATOMIC_RELAXED,
                             __HIP_MEMORY_SCOPE_AGENT);

    if (ks) {
      // WAR: owner must have consumed this parity slot (step tau-2)
      waitge(&consumed[fidx * 16], tau - 2);
      __builtin_amdgcn_fence(__ATOMIC_ACQUIRE, "agent");
      float* pb = partial + ((size_t)fidx * 2 + (tau & 1)) * 4096 + tid * 16;
      *(f32x4*)(pb + 0)  = acc00;
      *(f32x4*)(pb + 4)  = acc01;
      *(f32x4*)(pb + 8)  = acc10;
      *(f32x4*)(pb + 12) = acc11;
      __syncthreads();
      if (tid == 0) {
        __builtin_amdgcn_fence(__ATOMIC_RELEASE, "agent");
        __hip_atomic_store(&pseq[fidx * 16], tau, __ATOMIC_RELAXED,
                           __HIP_MEMORY_SCOPE_AGENT);
      }
    } else {
      waitge(&pseq[fidx * 16], tau);
      __builtin_amdgcn_fence(__ATOMIC_ACQUIRE, "agent");
      const float* pb = partial + ((size_t)fidx * 2 + (tau & 1)) * 4096 + tid * 16;
      f32x4 p0 = *(const f32x4*)(pb + 0);
      f32x4 p1 = *(const f32x4*)(pb + 4);
      f32x4 p2 = *(const f32x4*)(pb + 8);
      f32x4 p3 = *(const f32x4*)(pb + 12);
      acc00 += p0; acc01 += p1; acc10 += p2; acc11 += p3;
      __syncthreads();   // all threads' partial loads complete
      if (tid == 0) {
        __builtin_amdgcn_fence(__ATOMIC_RELEASE, "agent");
        __hip_atomic_store(&consumed[fidx * 16], tau, __ATOMIC_RELAXED,
                           __HIP_MEMORY_SCOPE_AGENT);
      }
      // WAR on X ring (3 bufs): all step tau-2 readers must be done
      if (tau >= 3) waitge(&xdone[(tau - 2) * 16], 256);

      bool past = tau < 64;
#define EPI1(ACC, F, G) do {                                                        \
      _Pragma("unroll")                                                             \
      for (int r = 0; r < 4; ++r) {                                                 \
        int m = m0 + wr * 32 + (F) * 16 + lg * 4 + r;                               \
        int col = n0 + wc * 32 + (G) * 16 + l15;                                    \
        float v = ACC[r]; float xv;                                                 \
        if (col < NYD) {                                                            \
          size_t oo = ((size_t)tau * BD + m) * NYD + col;                           \
          if (past) { float y = Y[oo]; out[oo] = v - y; xv = tanh_fast(y); }        \
          else      { out[oo] = v; xv = tanh_fast(v); }                             \
        } else xv = tanh_fast(v);                                                   \
        xdst[(size_t)m * NST + col] = f2bf(xv);                                     \
      }                                                                             \
    } while (0)
      EPI1(acc00, 0, 0); EPI1(acc01, 0, 1); EPI1(acc10, 1, 0); EPI1(acc11, 1, 1);
      __syncthreads();
      if (tid == 0) {
        __builtin_amdgcn_fence(__ATOMIC_RELEASE, "agent");
        __hip_atomic_fetch_add(&rdycnt[rel], 1, __ATOMIC_RELAXED,
                               __HIP_MEMORY_SCOPE_AGENT);
      }
    }
  }
#undef STAGE_PAIR
#undef PAIR_BODY
#undef EPI1
}

extern "C" void kernel_launch(void* const* d_in, const int* in_sizes, int n_in,
                              void* d_out, int out_size, void* d_ws, size_t ws_size,
                              hipStream_t stream) {
  (void)in_sizes; (void)n_in; (void)out_size; (void)ws_size;
  const float* U    = (const float*)d_in[0];   // [80][256][64]
  const float* Y    = (const float*)d_in[1];   // [64][256][128]
  const float* A    = (const float*)d_in[2];   // [2112][2048]
  const float* init = (const float*)d_in[3];   // [1][2048]
  float* out = (float*)d_out;                  // [80][256][128]

  char* ws = (char*)d_ws;
  int* flags    = (int*)ws;                    // 7424 ints (~29.7 KB region, 32 KB reserved)
  int* rdycnt   = flags;
  int* pseq     = flags + 2048;
  int* consumed = flags + 4096;
  int* xdone    = flags + 6144;
  u16* At = (u16*)(ws + 32768);                              //  8,650,752 B
  u16* X0 = (u16*)(ws + 8683520);                            //  1,048,576 B
  u16* X1 = (u16*)(ws + 8683520 + 1048576);                  //  1,048,576 B
  u16* X2 = (u16*)(ws + 8683520 + 2097152);                  //  1,048,576 B
  u16* Xu = (u16*)(ws + 11829248);                           //  2,621,440 B
  float* partial = (float*)(ws + 14450688);                  //  4,194,304 B (total ~18.6 MB)

  k_init<<<29, 256, 0, stream>>>(flags);
  k_prepA<<<dim3(32, 33), 256, 0, stream>>>(A, At);
  k_prepX0<<<dim3(256, 8), 256, 0, stream>>>(Y, init, X1, out);
  k_prepXu<<<(NSTEP * BD * NUD + 255) / 256, 256, 0, stream>>>(U, Xu);

  // static LDS 24,576 B + dynamic 73,728 B = 98,304 B/WG -> 1 WG/CU guaranteed
  // (VGPR ~340 independently forces 1 wave/SIMD), all 256 WGs co-resident.
  k_persist<<<256, 256, 73728, stream>>>(At, X0, X1, X2, Xu, partial,
                                         rdycnt, pseq, consumed, xdone, Y, out);
}